// Round 5
// baseline (224.138 us; speedup 1.0000x reference)
//
#include <hip/hip_runtime.h>
#include <stdint.h>

typedef __attribute__((ext_vector_type(4))) float f32x4;
typedef __attribute__((ext_vector_type(2))) float f32x2;
typedef __attribute__((ext_vector_type(8))) short s16x8;

// ---- geometry (fixed problem) ----
// x: (16,64,128,128) fp32; weight: (64,64,6,6) fp32 (Winograd-domain); bias fp32
// out: (16,64,128,128) fp32. 4x4 output tiles, nt=32/dim, 16384 tiles, PAD=1.
#define WB_BYTES 294912              // 36*64*64 bf16 relayout of weights

__device__ __forceinline__ short f2bf(float f) {
    uint32_t u = __builtin_bit_cast(uint32_t, f);
    u = u + 0x7FFFu + ((u >> 16) & 1u);          // round-to-nearest-even
    return (short)(u >> 16);
}

// dword-aligned (possibly 16B-misaligned) 16-byte global load
__device__ __forceinline__ f32x4 load4u(const float* p) {
    f32x4 v;
    __builtin_memcpy(&v, p, 16);
    return v;
}

// ---------------- Kernel 0: weight relayout fp32(co,cin,ab) -> bf16 [ab][co*64+cin] ----------------
__global__ __launch_bounds__(256) void wtrans(const float* __restrict__ wf, short* __restrict__ wb) {
    int tid = blockIdx.x * 256 + threadIdx.x;    // 0..4095  == co*64+cin
    const float* src = wf + tid * 36;
    float w[36];
#pragma unroll
    for (int i = 0; i < 9; i++) {
        f32x4 v = *(const f32x4*)(src + 4 * i);
        w[4*i+0] = v[0]; w[4*i+1] = v[1]; w[4*i+2] = v[2]; w[4*i+3] = v[3];
    }
#pragma unroll
    for (int ab = 0; ab < 36; ab++) wb[ab * 4096 + tid] = f2bf(w[ab]);  // coalesced per ab
}

// ---------------- Fused persistent kernel ----------------
// R2/R3 evidence: throughput-bound on per-CU LDS+VALU inside barrier phases, not
// latency-bound (8 vs 16 waves: same time). This version cuts DS work ~2x and
// pipelines staging:
//  - X: [32 ci][18 rows x 24 cols] stride 440 floats (1760B: bank 2-way=free, 16B
//    aligned). -1 col shift baked into GLOBAL load addr -> stage = 1 aligned
//    ds_write_b128/task, transform reads = 5x(b128+b64)/thread (was 36x b32).
//  - Vs: tile stride padded 32->40 shorts (80B) -> gemm ds_read_b128 conflict-free
//    (was 4-way @64B = the constant 2.78M conflict counter).
//  - persistent grid 256, 4 super-blocks each; r1 loads issued under transform0,
//    next-sb r0 loads issued under epilogue (T14); X double-buffered.
#define XCI 440                                  // floats per ci slice (18*24 + 8 pad)
__global__ __launch_bounds__(1024) void wino_fused(const float* __restrict__ x,
                                                   const short* __restrict__ wb,
                                                   const float* __restrict__ bias,
                                                   float* __restrict__ out) {
    __shared__ __align__(16) float SM[39680];    // 158,720 B -> 1 block/CU (regs cap anyway)
    float* X0 = SM;                              // [32][440] = 56,320 B
    float* X1 = SM + 14080;
    short* Vs = (short*)(SM + 28160);            // [36 ab][16 tile * 40] = 46,080 B
    float* P0 = SM;                              // epilogue partials (64 KB, aliases X0)
    float* P1 = SM + 16384;                      // (64 KB, aliases X1/Vs head)

    int t = threadIdx.x;
    int lane = t & 63;
    int w = t >> 6;                              // 0..15
    int cog = w >> 2;                            // 16-cout group
    int grp = w & 3;
    int sh = grp >> 1;                           // gemm a-half
    int bh = grp & 1;                            // gemm b-half
    int lo = lane & 15;                          // MFMA m/n: cout row (A) & tile (B)
    int kq = lane >> 4;

    int ci_t = t & 31;                           // transform: cin
    int tl_t = (t >> 5) & 15;                    // transform: tile
    int s2_t = t >> 9;                           // transform: a-half (rows 0-2 / 3-5)
    int tp = tl_t >> 2, tq = tl_t & 3;

    // stage task decomposition: s = i*1024 + t -> (ci, row, c4); constant per thread
    int tci[4], trow[4], tc4[4];
#pragma unroll
    for (int i = 0; i < 4; i++) {
        int s = i * 1024 + t;
        int ci = s / 108;                        // 18*6 tasks per ci
        int rem = s - ci * 108;
        int row = rem / 6;
        tci[i] = ci; trow[i] = row; tc4[i] = rem - row * 6;
    }
    bool v3 = t < 384;                           // task i=3 exists (3456-3072)

    float bv = bias[cog * 16 + kq * 4 + grp];    // phase-3 cout fixed per thread, hoisted

    f32x4 acc[9];
#pragma unroll
    for (int i = 0; i < 9; i++) acc[i] = (f32x4){0.f, 0.f, 0.f, 0.f};

    f32x4 L[4];                                  // in-flight staging registers

    auto issueLoads = [&](int vb, int r) {
        int n = vb >> 6, sb = vb & 63;
        int row0 = (sb >> 3) * 16 - 1;           // global row of local row 0
        int gc0 = (sb & 7) * 16 - 1;             // global col of local col 0 (the -1 shift)
        const float* xb = x + (size_t)n * 64 * 16384;
#pragma unroll
        for (int i = 0; i < 4; i++) {
            if (i < 3 || v3) {
                int gr = row0 + trow[i];
                int gc = gc0 + 4 * tc4[i];
                f32x4 v = (f32x4){0.f, 0.f, 0.f, 0.f};
                if ((unsigned)gr < 128u) {
                    const float* rowp = xb + (size_t)((r * 32 + tci[i]) * 128 + gr) * 128;
                    if (gc >= 0 && gc <= 124) {
                        v = load4u(rowp + gc);
                    } else {
                        if ((unsigned)(gc + 0) < 128u) v[0] = rowp[gc + 0];
                        if ((unsigned)(gc + 1) < 128u) v[1] = rowp[gc + 1];
                        if ((unsigned)(gc + 2) < 128u) v[2] = rowp[gc + 2];
                        if ((unsigned)(gc + 3) < 128u) v[3] = rowp[gc + 3];
                    }
                }
                L[i] = v;
            }
        }
    };

    auto writeX = [&](float* Xb) {
#pragma unroll
        for (int i = 0; i < 4; i++) {
            if (i < 3 || v3)
                *(f32x4*)&Xb[tci[i] * XCI + trow[i] * 24 + tc4[i] * 4] = L[i];  // aligned b128
        }
    };

    auto transform = [&](const float* Xbuf) {
        const float* Xb = Xbuf + ci_t * XCI + tp * 96 + tq * 4;
        f32x4 ra[5]; f32x2 rb[5];                // 5 rows: s2=0 -> m0..m4, s2=1 -> m1..m5
#pragma unroll
        for (int k = 0; k < 5; k++) {
            int off = (s2_t + k) * 24;
            ra[k] = *(const f32x4*)(Xb + off);   // 16B aligned
            rb[k] = *(const f32x2*)(Xb + off + 4);
        }
        float Ua[3][6];
#pragma unroll
        for (int c = 0; c < 6; c++) {
            float e0 = (c < 4) ? ra[0][c] : rb[0][c - 4];
            float e1 = (c < 4) ? ra[1][c] : rb[1][c - 4];
            float e2 = (c < 4) ? ra[2][c] : rb[2][c - 4];
            float e3 = (c < 4) ? ra[3][c] : rb[3][c - 4];
            float e4 = (c < 4) ? ra[4][c] : rb[4][c - 4];
            if (s2_t == 0) {                     // e = m0..m4
                float e = fmaf(-4.f, e2, e4);
                float f = fmaf(-4.f, e1, e3);
                Ua[0][c] = fmaf(4.f, e0 - e2, e4 - e2);
                Ua[1][c] = e + f;
                Ua[2][c] = e - f;
            } else {                             // e = m1..m5
                float g = e3 - e1;               // m4-m2
                float h = e2 - e0;               // m3-m1
                Ua[0][c] = fmaf(2.f, h, g);
                Ua[1][c] = fmaf(-2.f, h, g);
                Ua[2][c] = fmaf(4.f, e0 - e2, e4 - e2);  // 4(m1-m3)+(m5-m3)
            }
        }
        short* vb = Vs + tl_t * 40 + ci_t;
#pragma unroll
        for (int ar = 0; ar < 3; ar++) {
            float m0 = Ua[ar][0], m1 = Ua[ar][1], m2 = Ua[ar][2];
            float m3 = Ua[ar][3], m4 = Ua[ar][4], m5 = Ua[ar][5];
            float e = fmaf(-4.f, m2, m4);
            float f = fmaf(-4.f, m1, m3);
            float g = m4 - m2;
            float h = m3 - m1;
            int base = (s2_t * 3 + ar) * 6;
            vb[(base + 0) * 640] = f2bf(fmaf(4.f, m0 - m2, g));
            vb[(base + 1) * 640] = f2bf(e + f);
            vb[(base + 2) * 640] = f2bf(e - f);
            vb[(base + 3) * 640] = f2bf(fmaf(2.f, h, g));
            vb[(base + 4) * 640] = f2bf(fmaf(-2.f, h, g));
            vb[(base + 5) * 640] = f2bf(fmaf(4.f, m1 - m3, m5 - m3));
        }
    };

    auto gemmStep = [&](int r) {
        const short* wb_base = wb + (cog * 16 + lo) * 64 + r * 32 + kq * 8;
        const short* v_base = Vs + lo * 40 + kq * 8;     // 80B tile stride: conflict-free
#pragma unroll
        for (int ar = 0; ar < 3; ar++) {
#pragma unroll
            for (int br = 0; br < 3; br++) {
                int ab = (3 * sh + ar) * 6 + 3 * bh + br;
                s16x8 a0 = *(const s16x8*)(wb_base + ab * 4096);
                s16x8 b0 = *(const s16x8*)(v_base + ab * 640);
                acc[ar * 3 + br] = __builtin_amdgcn_mfma_f32_16x16x32_bf16(a0, b0, acc[ar * 3 + br], 0, 0, 0);
            }
        }
    };

    int vb0 = blockIdx.x * 4;
    issueLoads(vb0, 0);                          // prologue: only exposed HBM latency

    for (int it = 0; it < 4; ++it) {
        int vb = vb0 + it;
        int n = vb >> 6, sb = vb & 63;
        int p0_ = (sb >> 3) * 4;
        int q0_ = (sb & 7) * 4;

        writeX(X0);
        __syncthreads();                         // X0 visible
        issueLoads(vb, 1);                       // r1 in flight; consumed after transform (hidden)
        transform(X0);
        writeX(X1);                              // r1 regs -> X1 (vmcnt waits here, post-transform)
        __syncthreads();                         // Vs + X1 visible
        gemmStep(0);
        __syncthreads();                         // Vs reads done
        transform(X1);
        __syncthreads();                         // Vs visible
        gemmStep(1);
        __syncthreads();                         // Vs/X dead -> P alias safe

        if (it < 3) issueLoads(vb + 1, 0);       // prefetch next super-block r0 under epilogue

        int p = p0_ + (lo >> 2);
        int q = q0_ + (lo & 3);
        float* Pown = (sh == 0) ? P0 : P1;

        // D layout: col=lo (tile), row=kq*4+rr (cout in cog); acc[ar*3+br], a=3sh+ar, b=3bh+br
        if (bh == 0) {                           // phase 1: write partial (b=0,1,2)
#pragma unroll
            for (int rr = 0; rr < 4; rr++) {
                float z[4][3];
#pragma unroll
                for (int br = 0; br < 3; br++) {
                    float ma = acc[br][rr], mb = acc[3 + br][rr], mc = acc[6 + br][rr];
                    if (sh == 0) {
                        float s1 = mb + mc, d1 = mb - mc;
                        z[0][br] = ma + s1; z[1][br] = d1; z[2][br] = s1; z[3][br] = d1;
                    } else {
                        float sv = ma + mb, dv = ma - mb;
                        z[0][br] = sv; z[1][br] = 2.f * dv; z[2][br] = 4.f * sv;
                        z[3][br] = fmaf(8.f, dv, mc);
                    }
                }
#pragma unroll
                for (int xr = 0; xr < 4; xr++) {
                    float s1 = z[xr][1] + z[xr][2], d1 = z[xr][1] - z[xr][2];
                    f32x4 y;
                    y[0] = z[xr][0] + s1; y[1] = d1; y[2] = s1; y[3] = d1;
                    *(f32x4*)&Pown[cog * 4096 + (rr * 4 + xr) * 256 + lane * 4] = y;
                }
            }
        }
        __syncthreads();
        if (bh == 1) {                           // phase 2: add partial (b=3,4,5)
#pragma unroll
            for (int rr = 0; rr < 4; rr++) {
                float z[4][3];
#pragma unroll
                for (int br = 0; br < 3; br++) {
                    float ma = acc[br][rr], mb = acc[3 + br][rr], mc = acc[6 + br][rr];
                    if (sh == 0) {
                        float s1 = mb + mc, d1 = mb - mc;
                        z[0][br] = ma + s1; z[1][br] = d1; z[2][br] = s1; z[3][br] = d1;
                    } else {
                        float sv = ma + mb, dv = ma - mb;
                        z[0][br] = sv; z[1][br] = 2.f * dv; z[2][br] = 4.f * sv;
                        z[3][br] = fmaf(8.f, dv, mc);
                    }
                }
#pragma unroll
                for (int xr = 0; xr < 4; xr++) {
                    float s2 = z[xr][0] + z[xr][1], d2 = z[xr][0] - z[xr][1];
                    f32x4 y;
                    y[0] = s2; y[1] = 2.f * d2; y[2] = 4.f * s2;
                    y[3] = fmaf(8.f, d2, z[xr][2]);
                    float* pp = &Pown[cog * 4096 + (rr * 4 + xr) * 256 + lane * 4];
                    f32x4 old = *(const f32x4*)pp;
                    *(f32x4*)pp = old + y;
                }
            }
        }
        __syncthreads();
        // phase 3: all 16 waves store; wave (cog,grp) handles rr=grp
        {
            int rr = grp;
            int co = cog * 16 + kq * 4 + rr;
            float* ob = out + ((size_t)(n * 64 + co) * 128 + 4 * p) * 128 + 4 * q;
#pragma unroll
            for (int xr = 0; xr < 4; xr++) {
                int idx = cog * 4096 + (rr * 4 + xr) * 256 + lane * 4;
                f32x4 a0 = *(const f32x4*)&P0[idx];
                f32x4 a1 = *(const f32x4*)&P1[idx];
                f32x4 y;
                y[0] = a0[0] + a1[0] + bv;
                y[1] = a0[1] + a1[1] + bv;
                y[2] = a0[2] + a1[2] + bv;
                y[3] = a0[3] + a1[3] + bv;
                *(f32x4*)(ob + xr * 128) = y;
            }
        }
#pragma unroll
        for (int i = 0; i < 9; i++) acc[i] = (f32x4){0.f, 0.f, 0.f, 0.f};
        if (it < 3) __syncthreads();             // P reads done before next it's writeX(X0)
    }
}

extern "C" void kernel_launch(void* const* d_in, const int* in_sizes, int n_in,
                              void* d_out, int out_size, void* d_ws, size_t ws_size,
                              hipStream_t stream) {
    const float* x    = (const float*)d_in[0];
    const float* wf   = (const float*)d_in[1];
    const float* bias = (const float*)d_in[2];
    float* out = (float*)d_out;

    if (ws_size < WB_BYTES) return;              // need 295 KB scratch for bf16 weights
    short* wb = (short*)d_ws;

    wtrans<<<16, 256, 0, stream>>>(wf, wb);
    wino_fused<<<256, 1024, 0, stream>>>(x, wb, bias, out);
}

// Round 6
// 187.101 us; speedup vs baseline: 1.1980x; 1.1980x over previous
//
#include <hip/hip_runtime.h>
#include <stdint.h>

typedef __attribute__((ext_vector_type(4))) float f32x4;
typedef __attribute__((ext_vector_type(2))) float f32x2;
typedef __attribute__((ext_vector_type(8))) short s16x8;

// ---- geometry (fixed problem) ----
// x: (16,64,128,128) fp32; weight: (64,64,6,6) fp32 (Winograd-domain); bias fp32
// out: (16,64,128,128) fp32. 4x4 output tiles, nt=32/dim, 16384 tiles, PAD=1.
#define WB_BYTES 294912              // 36*64*64 bf16 relayout of weights

__device__ __forceinline__ short f2bf(float f) {
    uint32_t u = __builtin_bit_cast(uint32_t, f);
    u = u + 0x7FFFu + ((u >> 16) & 1u);          // round-to-nearest-even
    return (short)(u >> 16);
}

// dword-aligned (possibly 16B-misaligned) 16-byte global load
__device__ __forceinline__ f32x4 load4u(const float* p) {
    f32x4 v;
    __builtin_memcpy(&v, p, 16);
    return v;
}

// ---------------- Kernel 0: weight relayout fp32(co,cin,ab) -> bf16 [ab][co*64+cin] ----------------
__global__ __launch_bounds__(256) void wtrans(const float* __restrict__ wf, short* __restrict__ wb) {
    int tid = blockIdx.x * 256 + threadIdx.x;    // 0..4095  == co*64+cin
    const float* src = wf + tid * 36;
    float w[36];
#pragma unroll
    for (int i = 0; i < 9; i++) {
        f32x4 v = *(const f32x4*)(src + 4 * i);
        w[4*i+0] = v[0]; w[4*i+1] = v[1]; w[4*i+2] = v[2]; w[4*i+3] = v[3];
    }
#pragma unroll
    for (int ab = 0; ab < 36; ab++) wb[ab * 4096 + tid] = f2bf(w[ab]);  // coalesced per ab
}

// ---------------- Fused kernel (R3 structure + bank-correct wide-LDS layouts) ----------------
// Register budget (VERIFIED pool model, R0/R2/R3/R5): 2048 unified regs/CU; a
// 1024-thread block = 16 resident waves -> <=128 regs/wave (arch+acc). v5 held
// prefetch regs across barriers -> spill -> +233 MB scratch traffic. v6 holds
// NOTHING across phases: stage loads+writes immediately; demand ~110 < 128.
// LDS layouts (bank-derived):
//  - X [32 ci][436]: XCI=436 = 4*109, 109 odd -> ci*XCI mod 32 has period 8 ->
//    transform b128 reads hit each bank exactly 8 dwords/wave = minimal.
//    (v5's 440: period 4 -> 8-way conflict, the +0.9M counter regression.)
//  - Vs [36 ab][16 tile * 40]: 80B tile stride -> gemm ds_read_b128 minimal (verified
//    mechanism in v5: the R3 4-way @64B is gone).
//  - stage: one aligned ds_write_b128/task (col -1 shift baked into global addr).
//  - interior blocks (36/64): unguarded b128 loads, wave-uniform branch.
#define XCI 436                                  // 18*24=432 + 4 pad; ==4 mod 8 (bank period 8)
__global__ __launch_bounds__(1024) void wino_fused(const float* __restrict__ x,
                                                   const short* __restrict__ wb,
                                                   const float* __restrict__ bias,
                                                   float* __restrict__ out) {
    __shared__ __align__(16) float SM[32768];    // 131,072 B (1 block/CU; regs cap anyway)
    float* X = SM;                               // [32][436] = 55,808 B
    short* Vs = (short*)(SM + 13952);            // [36][640] shorts = 46,080 B (ends 101,888)
    float* P0 = SM;                              // epilogue partials sh=0 (64 KB, aliases X)
    float* P1 = SM + 16384;                      // sh=1 (64 KB, aliases Vs tail)

    int t = threadIdx.x;
    int lane = t & 63;
    int w = t >> 6;                              // 0..15
    int cog = w >> 2;                            // 16-cout group
    int grp = w & 3;
    int sh = grp >> 1;                           // gemm a-half
    int bh = grp & 1;                            // gemm b-half
    int lo = lane & 15;                          // MFMA m/n: cout row (A) & tile (B)
    int kq = lane >> 4;

    int ci_t = t & 31;                           // transform: cin
    int tl_t = (t >> 5) & 15;                    // transform: tile
    int s2_t = t >> 9;                           // transform: a-half (rows 0-2 / 3-5)
    int tp = tl_t >> 2, tq = tl_t & 3;

    int b = blockIdx.x;
    int n = b >> 6, sb = b & 63;
    int p0_ = (sb >> 3) * 4;                     // super-block tile origin
    int q0_ = (sb & 7) * 4;
    const float* xb = x + (size_t)n * 64 * 16384;
    int row0 = 4 * p0_ - 1;                      // global row of local row 0
    int gc0 = 4 * q0_ - 1;                       // global col of local col 0 (-1 shift baked in)
    int sr = sb >> 3, sc = sb & 7;
    bool interior = (sr >= 1) & (sr <= 6) & (sc >= 1) & (sc <= 6);

    float bv = bias[cog * 16 + kq * 4 + grp];    // phase-3 cout, hoisted (1 reg)

    f32x4 acc[9];
#pragma unroll
    for (int i = 0; i < 9; i++) acc[i] = (f32x4){0.f, 0.f, 0.f, 0.f};

#pragma unroll
    for (int r = 0; r < 2; r++) {
        // ---- stage X: 32 ci x 18 rows x 6 f4-cols (3456 tasks); load->write, no held regs ----
        const float* xrb = xb + (size_t)r * 32 * 16384;
        if (interior) {
#pragma unroll
            for (int i = 0; i < 4; i++) {
                if (i < 3 || t < 384) {
                    int s = i * 1024 + t;
                    int ci = s / 108;            // 18*6 tasks per ci
                    int rem = s - ci * 108;
                    int row = rem / 6;
                    int c4 = rem - row * 6;
                    f32x4 v = load4u(xrb + (size_t)(ci * 128 + row0 + row) * 128 + (gc0 + 4 * c4));
                    *(f32x4*)&X[ci * XCI + row * 24 + c4 * 4] = v;
                }
            }
        } else {
#pragma unroll
            for (int i = 0; i < 4; i++) {
                if (i < 3 || t < 384) {
                    int s = i * 1024 + t;
                    int ci = s / 108;
                    int rem = s - ci * 108;
                    int row = rem / 6;
                    int c4 = rem - row * 6;
                    int gr = row0 + row;
                    int gc = gc0 + 4 * c4;
                    f32x4 v = (f32x4){0.f, 0.f, 0.f, 0.f};
                    if ((unsigned)gr < 128u) {
                        const float* rowp = xrb + (size_t)(ci * 128 + gr) * 128;
                        if (gc >= 0 && gc <= 124) {
                            v = load4u(rowp + gc);
                        } else {
                            if ((unsigned)(gc + 0) < 128u) v[0] = rowp[gc + 0];
                            if ((unsigned)(gc + 1) < 128u) v[1] = rowp[gc + 1];
                            if ((unsigned)(gc + 2) < 128u) v[2] = rowp[gc + 2];
                            if ((unsigned)(gc + 3) < 128u) v[3] = rowp[gc + 3];
                        }
                    }
                    *(f32x4*)&X[ci * XCI + row * 24 + c4 * 4] = v;
                }
            }
        }
        __syncthreads();                         // X visible

        // ---- transform: 1 task/thread (s2-half, tile, cin); 5x(b128+b64) reads ----
        {
            const float* Xb = X + ci_t * XCI + tp * 96 + tq * 4;
            f32x4 ra[5]; f32x2 rb[5];            // 5 rows: s2=0 -> m0..m4, s2=1 -> m1..m5
#pragma unroll
            for (int k = 0; k < 5; k++) {
                int off = (s2_t + k) * 24;
                ra[k] = *(const f32x4*)(Xb + off);       // 16B aligned
                rb[k] = *(const f32x2*)(Xb + off + 4);
            }
            float Ua[3][6];
#pragma unroll
            for (int c = 0; c < 6; c++) {
                float e0 = (c < 4) ? ra[0][c] : rb[0][c - 4];
                float e1 = (c < 4) ? ra[1][c] : rb[1][c - 4];
                float e2 = (c < 4) ? ra[2][c] : rb[2][c - 4];
                float e3 = (c < 4) ? ra[3][c] : rb[3][c - 4];
                float e4 = (c < 4) ? ra[4][c] : rb[4][c - 4];
                if (s2_t == 0) {                 // e = m0..m4
                    float e = fmaf(-4.f, e2, e4);
                    float f = fmaf(-4.f, e1, e3);
                    Ua[0][c] = fmaf(4.f, e0 - e2, e4 - e2);
                    Ua[1][c] = e + f;
                    Ua[2][c] = e - f;
                } else {                         // e = m1..m5
                    float g = e3 - e1;           // m4-m2
                    float h = e2 - e0;           // m3-m1
                    Ua[0][c] = fmaf(2.f, h, g);
                    Ua[1][c] = fmaf(-2.f, h, g);
                    Ua[2][c] = fmaf(4.f, e0 - e2, e4 - e2);  // 4(m1-m3)+(m5-m3)
                }
            }
            short* vb = Vs + tl_t * 40 + ci_t;
#pragma unroll
            for (int ar = 0; ar < 3; ar++) {
                float m0 = Ua[ar][0], m1 = Ua[ar][1], m2 = Ua[ar][2];
                float m3 = Ua[ar][3], m4 = Ua[ar][4], m5 = Ua[ar][5];
                float e = fmaf(-4.f, m2, m4);
                float f = fmaf(-4.f, m1, m3);
                float g = m4 - m2;
                float h = m3 - m1;
                int base = (s2_t * 3 + ar) * 6;
                vb[(base + 0) * 640] = f2bf(fmaf(4.f, m0 - m2, g));
                vb[(base + 1) * 640] = f2bf(e + f);
                vb[(base + 2) * 640] = f2bf(e - f);
                vb[(base + 3) * 640] = f2bf(fmaf(2.f, h, g));
                vb[(base + 4) * 640] = f2bf(fmaf(-2.f, h, g));
                vb[(base + 5) * 640] = f2bf(fmaf(4.f, m1 - m3, m5 - m3));
            }
        }
        __syncthreads();                         // Vs visible

        // ---- GEMM: 9 MFMAs (K=32) on this wave's 3x3 ab-subtile; A from L2-hot wb ----
        {
            const short* wb_base = wb + (cog * 16 + lo) * 64 + r * 32 + kq * 8;
            const short* v_base = Vs + lo * 40 + kq * 8;     // 80B tile stride: bank-minimal
#pragma unroll
            for (int ar = 0; ar < 3; ar++) {
#pragma unroll
                for (int br = 0; br < 3; br++) {
                    int ab = (3 * sh + ar) * 6 + 3 * bh + br;
                    s16x8 a0 = *(const s16x8*)(wb_base + ab * 4096);
                    s16x8 b0 = *(const s16x8*)(v_base + ab * 640);
                    acc[ar * 3 + br] = __builtin_amdgcn_mfma_f32_16x16x32_bf16(a0, b0, acc[ar * 3 + br], 0, 0, 0);
                }
            }
        }
        // no trailing barrier: next r's post-stage sync orders gemm(Vs reads) vs
        // next transform(Vs writes); stage itself only touches X (disjoint from Vs).
    }

    // ---- epilogue: 4-way partial AT..AT^T, combine via P0/P1, parallel store ----
    // D layout: col=lo (tile), row=kq*4+rr (cout in cog); acc[ar*3+br], a=3sh+ar, b=3bh+br.
    __syncthreads();                             // all gemm done (P aliases X/Vs)
    int p = p0_ + (lo >> 2);
    int q = q0_ + (lo & 3);
    float* Pown = (sh == 0) ? P0 : P1;

    if (bh == 0) {                               // phase 1: write partial (b=0,1,2)
#pragma unroll
        for (int rr = 0; rr < 4; rr++) {
            float z[4][3];
#pragma unroll
            for (int br = 0; br < 3; br++) {
                float ma = acc[br][rr], mb = acc[3 + br][rr], mc = acc[6 + br][rr];
                if (sh == 0) {
                    float s1 = mb + mc, d1 = mb - mc;
                    z[0][br] = ma + s1; z[1][br] = d1; z[2][br] = s1; z[3][br] = d1;
                } else {
                    float sv = ma + mb, dv = ma - mb;
                    z[0][br] = sv; z[1][br] = 2.f * dv; z[2][br] = 4.f * sv;
                    z[3][br] = fmaf(8.f, dv, mc);
                }
            }
#pragma unroll
            for (int xr = 0; xr < 4; xr++) {
                float s1 = z[xr][1] + z[xr][2], d1 = z[xr][1] - z[xr][2];
                f32x4 y;
                y[0] = z[xr][0] + s1; y[1] = d1; y[2] = s1; y[3] = d1;
                *(f32x4*)&Pown[cog * 4096 + (rr * 4 + xr) * 256 + lane * 4] = y;
            }
        }
    }
    __syncthreads();
    if (bh == 1) {                               // phase 2: add partial (b=3,4,5)
#pragma unroll
        for (int rr = 0; rr < 4; rr++) {
            float z[4][3];
#pragma unroll
            for (int br = 0; br < 3; br++) {
                float ma = acc[br][rr], mb = acc[3 + br][rr], mc = acc[6 + br][rr];
                if (sh == 0) {
                    float s1 = mb + mc, d1 = mb - mc;
                    z[0][br] = ma + s1; z[1][br] = d1; z[2][br] = s1; z[3][br] = d1;
                } else {
                    float sv = ma + mb, dv = ma - mb;
                    z[0][br] = sv; z[1][br] = 2.f * dv; z[2][br] = 4.f * sv;
                    z[3][br] = fmaf(8.f, dv, mc);
                }
            }
#pragma unroll
            for (int xr = 0; xr < 4; xr++) {
                float s2 = z[xr][0] + z[xr][1], d2 = z[xr][0] - z[xr][1];
                f32x4 y;
                y[0] = s2; y[1] = 2.f * d2; y[2] = 4.f * s2;
                y[3] = fmaf(8.f, d2, z[xr][2]);
                float* pp = &Pown[cog * 4096 + (rr * 4 + xr) * 256 + lane * 4];
                f32x4 old = *(const f32x4*)pp;
                *(f32x4*)pp = old + y;
            }
        }
    }
    __syncthreads();
    // phase 3: all 16 waves store; wave (cog,grp) handles rr=grp
    {
        int rr = grp;
        int co = cog * 16 + kq * 4 + rr;
        float* ob = out + ((size_t)(n * 64 + co) * 128 + 4 * p) * 128 + 4 * q;
#pragma unroll
        for (int xr = 0; xr < 4; xr++) {
            int idx = cog * 4096 + (rr * 4 + xr) * 256 + lane * 4;
            f32x4 a0 = *(const f32x4*)&P0[idx];
            f32x4 a1 = *(const f32x4*)&P1[idx];
            f32x4 y;
            y[0] = a0[0] + a1[0] + bv;
            y[1] = a0[1] + a1[1] + bv;
            y[2] = a0[2] + a1[2] + bv;
            y[3] = a0[3] + a1[3] + bv;
            *(f32x4*)(ob + xr * 128) = y;
        }
    }
}

extern "C" void kernel_launch(void* const* d_in, const int* in_sizes, int n_in,
                              void* d_out, int out_size, void* d_ws, size_t ws_size,
                              hipStream_t stream) {
    const float* x    = (const float*)d_in[0];
    const float* wf   = (const float*)d_in[1];
    const float* bias = (const float*)d_in[2];
    float* out = (float*)d_out;

    if (ws_size < WB_BYTES) return;              // need 295 KB scratch for bf16 weights
    short* wb = (short*)d_ws;

    wtrans<<<16, 256, 0, stream>>>(wf, wb);
    wino_fused<<<1024, 1024, 0, stream>>>(x, wb, bias, out);
}